// Round 9
// baseline (198.412 us; speedup 1.0000x reference)
//
#include <hip/hip_runtime.h>

static constexpr int F = 128;   // feature width of x / hidden layers

typedef __attribute__((ext_vector_type(8))) short bf16x8;
typedef __attribute__((ext_vector_type(4))) float f32x4;

__device__ __forceinline__ unsigned short f2b(float f) {   // fp32 -> bf16 RNE
    unsigned int u = __float_as_uint(f);
    u += 0x7fffu + ((u >> 16) & 1u);
    return (unsigned short)(u >> 16);
}
__device__ __forceinline__ float b2f(unsigned int s) {     // low 16 bits -> fp32
    return __uint_as_float(s << 16);
}

// ---------------- prep: cvt x -> bf16, cvt/transpose weights, dst histogram ----------------
// (cnt AND cursor must be zeroed by the preceding hipMemsetAsync)
__global__ __launch_bounds__(256) void prep_kernel(const float* __restrict__ x,
                                                   unsigned short* __restrict__ xb, int n4,
                                                   const int* __restrict__ dst,
                                                   int* __restrict__ cnt, int nE,
                                                   const float* __restrict__ ws1, const float* __restrict__ wn1,
                                                   const float* __restrict__ ws2, const float* __restrict__ wn2,
                                                   const float* __restrict__ ws3, const float* __restrict__ wn3,
                                                   unsigned short* __restrict__ wt1,
                                                   unsigned short* __restrict__ wt2,
                                                   unsigned short* __restrict__ wt3) {
    const int id = blockIdx.x * 256 + threadIdx.x;
    if (id < n4) {
        const float4 v = reinterpret_cast<const float4*>(x)[id];
        uint2 o;
        o.x = (unsigned)f2b(v.x) | ((unsigned)f2b(v.y) << 16);
        o.y = (unsigned)f2b(v.z) | ((unsigned)f2b(v.w) << 16);
        reinterpret_cast<uint2*>(xb)[id] = o;
    }
    if (id < nE) atomicAdd(&cnt[dst[id]], 1);
    if (id < 128 * 256) {           // wt[col][256] concat(self, neigh), bf16
        const int k = id & 255, c = id >> 8;
        wt1[id] = f2b((k < 128) ? ws1[k * 128 + c] : wn1[(k - 128) * 128 + c]);
        wt2[id] = f2b((k < 128) ? ws2[k * 128 + c] : wn2[(k - 128) * 128 + c]);
    }
    if (id < 64 * 256) {
        const int k = id & 255, c = id >> 8;
        wt3[id] = f2b((k < 128) ? ws3[k * 64 + c] : wn3[(k - 128) * 64 + c]);
    }
}

// ---------------- one-kernel scan: block scan + atomic block base -> rowptr ----------------
// rowptr[v] = start of node v's edge range (block bases assigned by atomic cursor;
// non-deterministic base ORDER, but each node's edge set is unchanged). Also zeroes fillcnt.
__global__ __launch_bounds__(256) void scanAB_kernel(const int* __restrict__ cnt,
                                                     int* __restrict__ rowptr,
                                                     int* __restrict__ fillcnt,
                                                     int* __restrict__ cursor, int n) {
    __shared__ int s[256];
    __shared__ int base;
    const int tid = threadIdx.x;
    const int i = blockIdx.x * 256 + tid;
    const int v = (i < n) ? cnt[i] : 0;
    if (i < n) fillcnt[i] = 0;
    s[tid] = v;
    __syncthreads();
#pragma unroll
    for (int off = 1; off < 256; off <<= 1) {
        int t = (tid >= off) ? s[tid - off] : 0;
        __syncthreads();
        s[tid] += t;
        __syncthreads();
    }
    if (tid == 255) base = atomicAdd(cursor, s[255]);
    __syncthreads();
    if (i < n) rowptr[i] = base + s[tid] - v;   // exclusive within block + block base
}

// ---------------- CSR fill: compact ushort col (1.28 MB -> scatter absorbed by L2) ----------------
__global__ __launch_bounds__(256) void fill_kernel(const int* __restrict__ src,
                                                   const int* __restrict__ dst,
                                                   const int* __restrict__ rowptr,
                                                   int* __restrict__ fillcnt,
                                                   unsigned short* __restrict__ col, int nE) {
    const int e = blockIdx.x * 256 + threadIdx.x;
    if (e < nE) {
        const int d = dst[e];
        const int pos = atomicAdd(&fillcnt[d], 1);
        col[rowptr[d] + pos] = (unsigned short)src[e];
    }
}

// ---------------- gather: nb[v] = mean_{u in N(v)} xb[u]  (bf16 in/out, fp32 accum) ----------------
// 32 lanes per node, 8B per lane. Masked 16-deep loop: ALL edges (incl. tail) processed
// with 16 outstanding loads; clamped index + 0/1 fma weight handles the remainder
// (masked slots re-read row cp[0] -> L1 hit, weight 0).
__global__ __launch_bounds__(256) void gather_b_kernel(const unsigned short* __restrict__ xb,
                                                       const int* __restrict__ rowptr,
                                                       const int* __restrict__ deg_arr,
                                                       const unsigned short* __restrict__ col,
                                                       unsigned short* __restrict__ nb, int nNodes) {
    const int grp  = (blockIdx.x * 256 + threadIdx.x) >> 5;
    const int lane = threadIdx.x & 31;
    if (grp >= nNodes) return;
    const int beg = rowptr[grp];
    const int deg = deg_arr[grp];
    const unsigned short* __restrict__ cp = col + beg;
    const int q = lane << 2;                // ushort index, 4 bf16 per lane

    float a0[4] = {0.f, 0.f, 0.f, 0.f};
    float a1[4] = {0.f, 0.f, 0.f, 0.f};
    float a2[4] = {0.f, 0.f, 0.f, 0.f};
    float a3[4] = {0.f, 0.f, 0.f, 0.f};

    for (int j = 0; j < deg; j += 16) {
        int   idx[16];
        float wg[16];
#pragma unroll
        for (int m = 0; m < 16; ++m) {
            const int jm = j + m;
            idx[m] = cp[jm < deg ? jm : 0];
            wg[m]  = (jm < deg) ? 1.f : 0.f;
        }
        uint2 v[16];
#pragma unroll
        for (int m = 0; m < 16; ++m)
            v[m] = *reinterpret_cast<const uint2*>(xb + (size_t)idx[m] * F + q);
#pragma unroll
        for (int m = 0; m < 16; m += 4) {
            a0[0] = fmaf(b2f(v[m].x & 0xffffu), wg[m], a0[0]);
            a0[1] = fmaf(b2f(v[m].x >> 16),     wg[m], a0[1]);
            a0[2] = fmaf(b2f(v[m].y & 0xffffu), wg[m], a0[2]);
            a0[3] = fmaf(b2f(v[m].y >> 16),     wg[m], a0[3]);
            a1[0] = fmaf(b2f(v[m+1].x & 0xffffu), wg[m+1], a1[0]);
            a1[1] = fmaf(b2f(v[m+1].x >> 16),     wg[m+1], a1[1]);
            a1[2] = fmaf(b2f(v[m+1].y & 0xffffu), wg[m+1], a1[2]);
            a1[3] = fmaf(b2f(v[m+1].y >> 16),     wg[m+1], a1[3]);
            a2[0] = fmaf(b2f(v[m+2].x & 0xffffu), wg[m+2], a2[0]);
            a2[1] = fmaf(b2f(v[m+2].x >> 16),     wg[m+2], a2[1]);
            a2[2] = fmaf(b2f(v[m+2].y & 0xffffu), wg[m+2], a2[2]);
            a2[3] = fmaf(b2f(v[m+2].y >> 16),     wg[m+2], a2[3]);
            a3[0] = fmaf(b2f(v[m+3].x & 0xffffu), wg[m+3], a3[0]);
            a3[1] = fmaf(b2f(v[m+3].x >> 16),     wg[m+3], a3[1]);
            a3[2] = fmaf(b2f(v[m+3].y & 0xffffu), wg[m+3], a3[2]);
            a3[3] = fmaf(b2f(v[m+3].y >> 16),     wg[m+3], a3[3]);
        }
    }

    const float inv = 1.0f / (float)(deg > 1 ? deg : 1);
    uint2 o;
    o.x = (unsigned)f2b((a0[0] + a1[0] + a2[0] + a3[0]) * inv)
        | ((unsigned)f2b((a0[1] + a1[1] + a2[1] + a3[1]) * inv) << 16);
    o.y = (unsigned)f2b((a0[2] + a1[2] + a2[2] + a3[2]) * inv)
        | ((unsigned)f2b((a0[3] + a1[3] + a2[3] + a3[3]) * inv) << 16);
    *reinterpret_cast<uint2*>(nb + (size_t)grp * F + q) = o;
}

// ---------------- MFMA SAGE layer (col-split waves, B reused across 4 row-tiles) ----------------
// out[r] = act( [xb[r] | nb[r]] @ Wt^T + b ), K=256 concat, bf16 MFMA 16x16x32, fp32 acc.
template<int OUTF, bool RELU, bool OUTB>
__global__ __launch_bounds__(256, 4) void mfma_layer(const unsigned short* __restrict__ xb,
                                                     const unsigned short* __restrict__ nbuf,
                                                     const unsigned short* __restrict__ wt,
                                                     const float* __restrict__ bias,
                                                     void* __restrict__ outp, int nRows)
{
    constexpr int CT = OUTF / 64;          // col-tiles per wave (128->2, 64->1)
    __shared__ unsigned short Acat[64 * 256];   // 32 KB

    const int tid  = threadIdx.x;
    const int row0 = blockIdx.x * 64;

    // ---- stage 64 rows x (128 self + 128 neigh) bf16, 16B chunks, XOR swizzle ----
    for (int i = tid; i < 2048; i += 256) {
        const int r  = i >> 5;             // 0..63
        const int ch = i & 31;             // 0..31 (0-15 self, 16-31 neigh)
        const int g  = row0 + r;
        uint4 v = make_uint4(0u, 0u, 0u, 0u);
        if (g < nRows) {
            const unsigned short* s = (ch < 16) ? xb : nbuf;
            v = *reinterpret_cast<const uint4*>(s + (size_t)g * F + (ch & 15) * 8);
        }
        const int off = (ch * 16) ^ ((r & 7) << 4);
        *reinterpret_cast<uint4*>(reinterpret_cast<char*>(Acat) + r * 512 + off) = v;
    }
    __syncthreads();

    const int lane = tid & 63;
    const int w    = tid >> 6;             // wave 0..3 -> col block w*(OUTF/4)
    const int lm   = lane & 15;
    const int lq   = lane >> 4;            // 0..3
    const int colBase = w * (OUTF / 4);

    f32x4 acc[4][CT];
#pragma unroll
    for (int rt = 0; rt < 4; ++rt)
#pragma unroll
        for (int c = 0; c < CT; ++c) acc[rt][c] = f32x4{0.f, 0.f, 0.f, 0.f};

    const char* abase = reinterpret_cast<const char*>(Acat);

#pragma unroll
    for (int k0 = 0; k0 < 256; k0 += 32) {
        bf16x8 b[CT];
#pragma unroll
        for (int c = 0; c < CT; ++c)
            b[c] = *reinterpret_cast<const bf16x8*>(
                wt + (size_t)(colBase + c * 16 + lm) * 256 + k0 + lq * 8);
#pragma unroll
        for (int rt = 0; rt < 4; ++rt) {
            const int arow = rt * 16 + lm;
            const int aoff = (k0 * 2 + lq * 16) ^ ((arow & 7) << 4);
            const bf16x8 a = *reinterpret_cast<const bf16x8*>(abase + arow * 512 + aoff);
#pragma unroll
            for (int c = 0; c < CT; ++c)
                acc[rt][c] = __builtin_amdgcn_mfma_f32_16x16x32_bf16(a, b[c], acc[rt][c], 0, 0, 0);
        }
    }

    // ---- epilogue: C/D layout col=lane&15, row=(lane>>4)*4+i (m89-verified) ----
#pragma unroll
    for (int rt = 0; rt < 4; ++rt) {
#pragma unroll
        for (int c = 0; c < CT; ++c) {
            const int colIdx = colBase + c * 16 + lm;
            const float bv = bias[colIdx];
#pragma unroll
            for (int i = 0; i < 4; ++i) {
                const int grow = row0 + rt * 16 + lq * 4 + i;
                if (grow >= nRows) continue;
                float v = acc[rt][c][i] + bv;
                if (RELU) v = fmaxf(v, 0.f);
                if (OUTB) ((unsigned short*)outp)[(size_t)grow * F + colIdx] = f2b(v);
                else      ((float*)outp)[(size_t)grow * OUTF + colIdx] = v;
            }
        }
    }
}

extern "C" void kernel_launch(void* const* d_in, const int* in_sizes, int n_in,
                              void* d_out, int out_size, void* d_ws, size_t ws_size,
                              hipStream_t stream) {
    const float* x   = (const float*)d_in[0];
    const int*   src = (const int*)  d_in[1];
    const int*   dst = (const int*)  d_in[2];
    const float* ws1 = (const float*)d_in[3];
    const float* wn1 = (const float*)d_in[4];
    const float* b1  = (const float*)d_in[5];
    const float* ws2 = (const float*)d_in[6];
    const float* wn2 = (const float*)d_in[7];
    const float* b2  = (const float*)d_in[8];
    const float* ws3 = (const float*)d_in[9];
    const float* wn3 = (const float*)d_in[10];
    const float* b3  = (const float*)d_in[11];
    float* out = (float*)d_out;

    const int N = in_sizes[0] / F;   // 50000
    const int E = in_sizes[1];       // 640000

    const int nScanBlocks = (N + 255) / 256;   // 196

    // ---- workspace: [cnt | cursor] | rowptr | fillcnt | colu(ushort) | xb | nb | h1b | h2b | wt ----
    char* w = (char*)d_ws;
    const size_t cntBytes = ((size_t)N * 4 + 511) & ~(size_t)511;   // cnt
    const size_t curBytes = 512;                                    // cursor (zeroed with cnt)
    const size_t rpBytes  = ((size_t)N * 4 + 511) & ~(size_t)511;
    const size_t fcBytes  = rpBytes;
    const size_t colBytes = ((size_t)E * 2 + 511) & ~(size_t)511;
    int*            cnt     = (int*)(w);
    int*            cursor  = (int*)(w + cntBytes);
    int*            rowptr  = (int*)(w + cntBytes + curBytes);
    int*            fillcnt = (int*)(w + cntBytes + curBytes + rpBytes);
    unsigned short* colu    = (unsigned short*)(w + cntBytes + curBytes + rpBytes + fcBytes);
    unsigned short* xb      = (unsigned short*)(w + cntBytes + curBytes + rpBytes + fcBytes + colBytes);
    unsigned short* nb      = xb  + (size_t)N * F;
    unsigned short* h1b     = nb  + (size_t)N * F;
    unsigned short* h2b     = h1b + (size_t)N * F;
    unsigned short* wt1     = h2b + (size_t)N * F;
    unsigned short* wt2     = wt1 + 128 * 256;
    unsigned short* wt3     = wt2 + 128 * 256;

    const dim3 blk(256);
    const int n4         = N * F / 4;
    const int prepGrid   = (n4 + 255) / 256;
    const int edgeGrid   = (E + 255) / 256;
    const int gatherGrid = (int)(((size_t)N * 32 + 255) / 256);
    const int mfmaGrid   = (N + 63) / 64;

    // ---- build compact CSR: memset -> prep(hist+cvt) -> scanAB -> fill ----
    hipMemsetAsync(cnt, 0, cntBytes + curBytes, stream);
    prep_kernel<<<prepGrid, blk, 0, stream>>>(x, xb, n4, dst, cnt, E,
                                              ws1, wn1, ws2, wn2, ws3, wn3, wt1, wt2, wt3);
    scanAB_kernel<<<nScanBlocks, blk, 0, stream>>>(cnt, rowptr, fillcnt, cursor, N);
    fill_kernel<<<edgeGrid, blk, 0, stream>>>(src, dst, rowptr, fillcnt, colu, E);

    // ---- three layers: gather (bf16) + MFMA GEMM ----
    gather_b_kernel<<<gatherGrid, blk, 0, stream>>>(xb, rowptr, cnt, colu, nb, N);
    mfma_layer<128, true,  true ><<<mfmaGrid, blk, 0, stream>>>(xb,  nb, wt1, b1, h1b, N);

    gather_b_kernel<<<gatherGrid, blk, 0, stream>>>(h1b, rowptr, cnt, colu, nb, N);
    mfma_layer<128, true,  true ><<<mfmaGrid, blk, 0, stream>>>(h1b, nb, wt2, b2, h2b, N);

    gather_b_kernel<<<gatherGrid, blk, 0, stream>>>(h2b, rowptr, cnt, colu, nb, N);
    mfma_layer<64,  false, false><<<mfmaGrid, blk, 0, stream>>>(h2b, nb, wt3, b3, out, N);
}

// Round 10
// 188.355 us; speedup vs baseline: 1.0534x; 1.0534x over previous
//
#include <hip/hip_runtime.h>

static constexpr int F = 128;   // feature width of x / hidden layers

typedef __attribute__((ext_vector_type(8))) short bf16x8;
typedef __attribute__((ext_vector_type(4))) float f32x4;

__device__ __forceinline__ unsigned short f2b(float f) {   // fp32 -> bf16 RNE
    unsigned int u = __float_as_uint(f);
    u += 0x7fffu + ((u >> 16) & 1u);
    return (unsigned short)(u >> 16);
}
__device__ __forceinline__ float b2f(unsigned int s) {     // low 16 bits -> fp32
    return __uint_as_float(s << 16);
}

// ---------------- prep: cvt x -> bf16, cvt/transpose weights, dst histogram ----------------
// (cnt AND cursor must be zeroed by the preceding hipMemsetAsync)
__global__ __launch_bounds__(256) void prep_kernel(const float* __restrict__ x,
                                                   unsigned short* __restrict__ xb, int n4,
                                                   const int* __restrict__ dst,
                                                   int* __restrict__ cnt, int nE,
                                                   const float* __restrict__ ws1, const float* __restrict__ wn1,
                                                   const float* __restrict__ ws2, const float* __restrict__ wn2,
                                                   const float* __restrict__ ws3, const float* __restrict__ wn3,
                                                   unsigned short* __restrict__ wt1,
                                                   unsigned short* __restrict__ wt2,
                                                   unsigned short* __restrict__ wt3d) {
    const int id = blockIdx.x * 256 + threadIdx.x;
    if (id < n4) {
        const float4 v = reinterpret_cast<const float4*>(x)[id];
        uint2 o;
        o.x = (unsigned)f2b(v.x) | ((unsigned)f2b(v.y) << 16);
        o.y = (unsigned)f2b(v.z) | ((unsigned)f2b(v.w) << 16);
        reinterpret_cast<uint2*>(xb)[id] = o;
    }
    if (id < nE) atomicAdd(&cnt[dst[id]], 1);
    if (id < 128 * 256) {           // wt[col][256] concat(self, neigh), bf16, K=256
        const int k = id & 255, c = id >> 8;
        wt1[id] = f2b((k < 128) ? ws1[k * 128 + c] : wn1[(k - 128) * 128 + c]);
        wt2[id] = f2b((k < 128) ? ws2[k * 128 + c] : wn2[(k - 128) * 128 + c]);
    }
    if (id < 128 * 128) {           // layer-3 dual: wt3d[c][k], c<64 self, c>=64 neigh, K=128
        const int k = id & 127, c = id >> 7;
        wt3d[id] = f2b((c < 64) ? ws3[k * 64 + c] : wn3[k * 64 + (c - 64)]);
    }
}

// ---------------- one-kernel scan: block scan + atomic block base -> rowptr ----------------
__global__ __launch_bounds__(256) void scanAB_kernel(const int* __restrict__ cnt,
                                                     int* __restrict__ rowptr,
                                                     int* __restrict__ fillcnt,
                                                     int* __restrict__ cursor, int n) {
    __shared__ int s[256];
    __shared__ int base;
    const int tid = threadIdx.x;
    const int i = blockIdx.x * 256 + tid;
    const int v = (i < n) ? cnt[i] : 0;
    if (i < n) fillcnt[i] = 0;
    s[tid] = v;
    __syncthreads();
#pragma unroll
    for (int off = 1; off < 256; off <<= 1) {
        int t = (tid >= off) ? s[tid - off] : 0;
        __syncthreads();
        s[tid] += t;
        __syncthreads();
    }
    if (tid == 255) base = atomicAdd(cursor, s[255]);
    __syncthreads();
    if (i < n) rowptr[i] = base + s[tid] - v;   // exclusive within block + block base
}

// ---------------- CSR fill: compact ushort col (1.28 MB -> scatter absorbed by L2) ----------------
__global__ __launch_bounds__(256) void fill_kernel(const int* __restrict__ src,
                                                   const int* __restrict__ dst,
                                                   const int* __restrict__ rowptr,
                                                   int* __restrict__ fillcnt,
                                                   unsigned short* __restrict__ col, int nE) {
    const int e = blockIdx.x * 256 + threadIdx.x;
    if (e < nE) {
        const int d = dst[e];
        const int pos = atomicAdd(&fillcnt[d], 1);
        col[rowptr[d] + pos] = (unsigned short)src[e];
    }
}

// ---------------- gather: nb[v] = mean_{u in N(v)} xb[u]  (bf16 in/out, fp32 accum) ----------------
// 16 lanes per node, 16B (8 bf16) per lane -> full 256B row per neighbor load.
// 4 nodes per wave x 8-deep masked loop = 32 outstanding 16B loads per wave.
__global__ __launch_bounds__(256) void gather_b_kernel(const unsigned short* __restrict__ xb,
                                                       const int* __restrict__ rowptr,
                                                       const int* __restrict__ deg_arr,
                                                       const unsigned short* __restrict__ col,
                                                       unsigned short* __restrict__ nb, int nNodes) {
    const int grp  = (blockIdx.x * 256 + threadIdx.x) >> 4;
    const int lane = threadIdx.x & 15;
    if (grp >= nNodes) return;
    const int beg = rowptr[grp];
    const int deg = deg_arr[grp];
    const unsigned short* __restrict__ cp = col + beg;
    const int q = lane << 3;                // ushort index, 8 bf16 per lane

    float acc[8] = {0.f, 0.f, 0.f, 0.f, 0.f, 0.f, 0.f, 0.f};

    for (int j = 0; j < deg; j += 8) {
        int   idx[8];
        float wg[8];
#pragma unroll
        for (int m = 0; m < 8; ++m) {
            const int jm = j + m;
            idx[m] = cp[jm < deg ? jm : 0];
            wg[m]  = (jm < deg) ? 1.f : 0.f;
        }
        uint4 v[8];
#pragma unroll
        for (int m = 0; m < 8; ++m)
            v[m] = *reinterpret_cast<const uint4*>(xb + (size_t)idx[m] * F + q);
#pragma unroll
        for (int m = 0; m < 8; ++m) {
            acc[0] = fmaf(b2f(v[m].x & 0xffffu), wg[m], acc[0]);
            acc[1] = fmaf(b2f(v[m].x >> 16),     wg[m], acc[1]);
            acc[2] = fmaf(b2f(v[m].y & 0xffffu), wg[m], acc[2]);
            acc[3] = fmaf(b2f(v[m].y >> 16),     wg[m], acc[3]);
            acc[4] = fmaf(b2f(v[m].z & 0xffffu), wg[m], acc[4]);
            acc[5] = fmaf(b2f(v[m].z >> 16),     wg[m], acc[5]);
            acc[6] = fmaf(b2f(v[m].w & 0xffffu), wg[m], acc[6]);
            acc[7] = fmaf(b2f(v[m].w >> 16),     wg[m], acc[7]);
        }
    }

    const float inv = 1.0f / (float)(deg > 1 ? deg : 1);
    uint4 o;
    o.x = (unsigned)f2b(acc[0] * inv) | ((unsigned)f2b(acc[1] * inv) << 16);
    o.y = (unsigned)f2b(acc[2] * inv) | ((unsigned)f2b(acc[3] * inv) << 16);
    o.z = (unsigned)f2b(acc[4] * inv) | ((unsigned)f2b(acc[5] * inv) << 16);
    o.w = (unsigned)f2b(acc[6] * inv) | ((unsigned)f2b(acc[7] * inv) << 16);
    *reinterpret_cast<uint4*>(nb + (size_t)grp * F + q) = o;
}

// ---------------- final gather+add: out[v] = ys3[v] + mean_{u in N(v)} yn3[u] ----------------
// yn3 rows are 64 bf16 = 128B (half the traffic of a 256B x-row). fp32 out.
__global__ __launch_bounds__(256) void gather_f_kernel(const float* __restrict__ ys3,
                                                       const unsigned short* __restrict__ yn3,
                                                       const int* __restrict__ rowptr,
                                                       const int* __restrict__ deg_arr,
                                                       const unsigned short* __restrict__ col,
                                                       float* __restrict__ out, int nNodes) {
    const int grp  = (blockIdx.x * 256 + threadIdx.x) >> 4;
    const int lane = threadIdx.x & 15;
    if (grp >= nNodes) return;
    const int beg = rowptr[grp];
    const int deg = deg_arr[grp];
    const unsigned short* __restrict__ cp = col + beg;
    const int q = lane << 2;                // ushort index, 4 bf16 per lane (64/row)

    float a0 = 0.f, a1 = 0.f, a2 = 0.f, a3 = 0.f;

    for (int j = 0; j < deg; j += 8) {
        int   idx[8];
        float wg[8];
#pragma unroll
        for (int m = 0; m < 8; ++m) {
            const int jm = j + m;
            idx[m] = cp[jm < deg ? jm : 0];
            wg[m]  = (jm < deg) ? 1.f : 0.f;
        }
        uint2 v[8];
#pragma unroll
        for (int m = 0; m < 8; ++m)
            v[m] = *reinterpret_cast<const uint2*>(yn3 + (size_t)idx[m] * 64 + q);
#pragma unroll
        for (int m = 0; m < 8; ++m) {
            a0 = fmaf(b2f(v[m].x & 0xffffu), wg[m], a0);
            a1 = fmaf(b2f(v[m].x >> 16),     wg[m], a1);
            a2 = fmaf(b2f(v[m].y & 0xffffu), wg[m], a2);
            a3 = fmaf(b2f(v[m].y >> 16),     wg[m], a3);
        }
    }

    const float inv = 1.0f / (float)(deg > 1 ? deg : 1);
    const float4 s = *reinterpret_cast<const float4*>(ys3 + (size_t)grp * 64 + q);
    float4 o;
    o.x = s.x + a0 * inv;
    o.y = s.y + a1 * inv;
    o.z = s.z + a2 * inv;
    o.w = s.w + a3 * inv;
    *reinterpret_cast<float4*>(out + (size_t)grp * 64 + q) = o;
}

// ---------------- MFMA SAGE layer (K=256 concat, col-split waves, B reused x4) ----------------
template<int OUTF, bool RELU, bool OUTB>
__global__ __launch_bounds__(256, 4) void mfma_layer(const unsigned short* __restrict__ xb,
                                                     const unsigned short* __restrict__ nbuf,
                                                     const unsigned short* __restrict__ wt,
                                                     const float* __restrict__ bias,
                                                     void* __restrict__ outp, int nRows)
{
    constexpr int CT = OUTF / 64;          // col-tiles per wave (128->2, 64->1)
    __shared__ unsigned short Acat[64 * 256];   // 32 KB

    const int tid  = threadIdx.x;
    const int row0 = blockIdx.x * 64;

    for (int i = tid; i < 2048; i += 256) {
        const int r  = i >> 5;
        const int ch = i & 31;             // 0-15 self, 16-31 neigh
        const int g  = row0 + r;
        uint4 v = make_uint4(0u, 0u, 0u, 0u);
        if (g < nRows) {
            const unsigned short* s = (ch < 16) ? xb : nbuf;
            v = *reinterpret_cast<const uint4*>(s + (size_t)g * F + (ch & 15) * 8);
        }
        const int off = (ch * 16) ^ ((r & 7) << 4);
        *reinterpret_cast<uint4*>(reinterpret_cast<char*>(Acat) + r * 512 + off) = v;
    }
    __syncthreads();

    const int lane = tid & 63;
    const int w    = tid >> 6;
    const int lm   = lane & 15;
    const int lq   = lane >> 4;
    const int colBase = w * (OUTF / 4);

    f32x4 acc[4][CT];
#pragma unroll
    for (int rt = 0; rt < 4; ++rt)
#pragma unroll
        for (int c = 0; c < CT; ++c) acc[rt][c] = f32x4{0.f, 0.f, 0.f, 0.f};

    const char* abase = reinterpret_cast<const char*>(Acat);

#pragma unroll
    for (int k0 = 0; k0 < 256; k0 += 32) {
        bf16x8 b[CT];
#pragma unroll
        for (int c = 0; c < CT; ++c)
            b[c] = *reinterpret_cast<const bf16x8*>(
                wt + (size_t)(colBase + c * 16 + lm) * 256 + k0 + lq * 8);
#pragma unroll
        for (int rt = 0; rt < 4; ++rt) {
            const int arow = rt * 16 + lm;
            const int aoff = (k0 * 2 + lq * 16) ^ ((arow & 7) << 4);
            const bf16x8 a = *reinterpret_cast<const bf16x8*>(abase + arow * 512 + aoff);
#pragma unroll
            for (int c = 0; c < CT; ++c)
                acc[rt][c] = __builtin_amdgcn_mfma_f32_16x16x32_bf16(a, b[c], acc[rt][c], 0, 0, 0);
        }
    }

#pragma unroll
    for (int rt = 0; rt < 4; ++rt) {
#pragma unroll
        for (int c = 0; c < CT; ++c) {
            const int colIdx = colBase + c * 16 + lm;
            const float bv = bias[colIdx];
#pragma unroll
            for (int i = 0; i < 4; ++i) {
                const int grow = row0 + rt * 16 + lq * 4 + i;
                if (grow >= nRows) continue;
                float v = acc[rt][c][i] + bv;
                if (RELU) v = fmaxf(v, 0.f);
                if (OUTB) ((unsigned short*)outp)[(size_t)grow * F + colIdx] = f2b(v);
                else      ((float*)outp)[(size_t)grow * OUTF + colIdx] = v;
            }
        }
    }
}

// ---------------- layer-3 dual GEMM: ys3 = h2@Ws3+b3 (fp32), yn3 = h2@Wn3 (bf16) ----------------
// K=128 (no concat), 128 output cols: 0-63 self, 64-127 neigh. wt3d[c][k].
__global__ __launch_bounds__(256, 4) void mfma_dual(const unsigned short* __restrict__ h2b,
                                                    const unsigned short* __restrict__ wt3d,
                                                    const float* __restrict__ bias,
                                                    float* __restrict__ ys3,
                                                    unsigned short* __restrict__ yn3, int nRows)
{
    __shared__ unsigned short Acat[64 * 128];   // 16 KB

    const int tid  = threadIdx.x;
    const int row0 = blockIdx.x * 64;

    for (int i = tid; i < 1024; i += 256) {
        const int r  = i >> 4;
        const int ch = i & 15;
        const int g  = row0 + r;
        uint4 v = make_uint4(0u, 0u, 0u, 0u);
        if (g < nRows)
            v = *reinterpret_cast<const uint4*>(h2b + (size_t)g * F + ch * 8);
        const int off = (ch * 16) ^ ((r & 7) << 4);
        *reinterpret_cast<uint4*>(reinterpret_cast<char*>(Acat) + r * 256 + off) = v;
    }
    __syncthreads();

    const int lane = tid & 63;
    const int w    = tid >> 6;             // wave 0..3 -> col block w*32
    const int lm   = lane & 15;
    const int lq   = lane >> 4;
    const int colBase = w * 32;

    f32x4 acc[4][2];
#pragma unroll
    for (int rt = 0; rt < 4; ++rt) {
        acc[rt][0] = f32x4{0.f, 0.f, 0.f, 0.f};
        acc[rt][1] = f32x4{0.f, 0.f, 0.f, 0.f};
    }

    const char* abase = reinterpret_cast<const char*>(Acat);

#pragma unroll
    for (int k0 = 0; k0 < 128; k0 += 32) {
        bf16x8 b[2];
#pragma unroll
        for (int c = 0; c < 2; ++c)
            b[c] = *reinterpret_cast<const bf16x8*>(
                wt3d + (size_t)(colBase + c * 16 + lm) * 128 + k0 + lq * 8);
#pragma unroll
        for (int rt = 0; rt < 4; ++rt) {
            const int arow = rt * 16 + lm;
            const int aoff = (k0 * 2 + lq * 16) ^ ((arow & 7) << 4);
            const bf16x8 a = *reinterpret_cast<const bf16x8*>(abase + arow * 256 + aoff);
#pragma unroll
            for (int c = 0; c < 2; ++c)
                acc[rt][c] = __builtin_amdgcn_mfma_f32_16x16x32_bf16(a, b[c], acc[rt][c], 0, 0, 0);
        }
    }

#pragma unroll
    for (int rt = 0; rt < 4; ++rt) {
#pragma unroll
        for (int c = 0; c < 2; ++c) {
            const int colIdx = colBase + c * 16 + lm;
#pragma unroll
            for (int i = 0; i < 4; ++i) {
                const int grow = row0 + rt * 16 + lq * 4 + i;
                if (grow >= nRows) continue;
                if (colIdx < 64) {
                    ys3[(size_t)grow * 64 + colIdx] = acc[rt][c][i] + bias[colIdx];
                } else {
                    yn3[(size_t)grow * 64 + (colIdx - 64)] = f2b(acc[rt][c][i]);
                }
            }
        }
    }
}

extern "C" void kernel_launch(void* const* d_in, const int* in_sizes, int n_in,
                              void* d_out, int out_size, void* d_ws, size_t ws_size,
                              hipStream_t stream) {
    const float* x   = (const float*)d_in[0];
    const int*   src = (const int*)  d_in[1];
    const int*   dst = (const int*)  d_in[2];
    const float* ws1 = (const float*)d_in[3];
    const float* wn1 = (const float*)d_in[4];
    const float* b1  = (const float*)d_in[5];
    const float* ws2 = (const float*)d_in[6];
    const float* wn2 = (const float*)d_in[7];
    const float* b2  = (const float*)d_in[8];
    const float* ws3 = (const float*)d_in[9];
    const float* wn3 = (const float*)d_in[10];
    const float* b3  = (const float*)d_in[11];
    float* out = (float*)d_out;

    const int N = in_sizes[0] / F;   // 50000
    const int E = in_sizes[1];       // 640000

    const int nScanBlocks = (N + 255) / 256;   // 196

    // ---- workspace: [cnt|cursor] | rowptr | fillcnt | colu | xb | nb | h1b | h2b | ys3 | yn3 | wt ----
    char* w = (char*)d_ws;
    const size_t cntBytes = ((size_t)N * 4 + 511) & ~(size_t)511;
    const size_t curBytes = 512;
    const size_t rpBytes  = ((size_t)N * 4 + 511) & ~(size_t)511;
    const size_t fcBytes  = rpBytes;
    const size_t colBytes = ((size_t)E * 2 + 511) & ~(size_t)511;
    int*            cnt     = (int*)(w);
    int*            cursor  = (int*)(w + cntBytes);
    int*            rowptr  = (int*)(w + cntBytes + curBytes);
    int*            fillcnt = (int*)(w + cntBytes + curBytes + rpBytes);
    unsigned short* colu    = (unsigned short*)(w + cntBytes + curBytes + rpBytes + fcBytes);
    unsigned short* xb      = (unsigned short*)(w + cntBytes + curBytes + rpBytes + fcBytes + colBytes);
    unsigned short* nb      = xb  + (size_t)N * F;
    unsigned short* h1b     = nb  + (size_t)N * F;
    unsigned short* h2b     = h1b + (size_t)N * F;
    unsigned short* yn3     = h2b + (size_t)N * F;          // N*64 bf16
    float*          ys3     = (float*)(yn3 + (size_t)N * 64);
    unsigned short* wt1     = (unsigned short*)(ys3 + (size_t)N * 64);
    unsigned short* wt2     = wt1 + 128 * 256;
    unsigned short* wt3d    = wt2 + 128 * 256;              // 128 cols x 128 K

    const dim3 blk(256);
    const int n4         = N * F / 4;
    const int prepGrid   = (n4 + 255) / 256;
    const int edgeGrid   = (E + 255) / 256;
    const int gatherGrid = (int)(((size_t)N * 16 + 255) / 256);
    const int mfmaGrid   = (N + 63) / 64;

    // ---- build compact CSR: memset -> prep(hist+cvt) -> scanAB -> fill ----
    hipMemsetAsync(cnt, 0, cntBytes + curBytes, stream);
    prep_kernel<<<prepGrid, blk, 0, stream>>>(x, xb, n4, dst, cnt, E,
                                              ws1, wn1, ws2, wn2, ws3, wn3, wt1, wt2, wt3d);
    scanAB_kernel<<<nScanBlocks, blk, 0, stream>>>(cnt, rowptr, fillcnt, cursor, N);
    fill_kernel<<<edgeGrid, blk, 0, stream>>>(src, dst, rowptr, fillcnt, colu, E);

    // ---- layers 1,2: gather (bf16) + MFMA GEMM ----
    gather_b_kernel<<<gatherGrid, blk, 0, stream>>>(xb, rowptr, cnt, colu, nb, N);
    mfma_layer<128, true,  true ><<<mfmaGrid, blk, 0, stream>>>(xb,  nb, wt1, b1, h1b, N);

    gather_b_kernel<<<gatherGrid, blk, 0, stream>>>(h1b, rowptr, cnt, colu, nb, N);
    mfma_layer<128, true,  true ><<<mfmaGrid, blk, 0, stream>>>(h1b, nb, wt2, b2, h2b, N);

    // ---- layer 3 via linearity: dual GEMM first, then 128B-row gather + add -> out ----
    mfma_dual<<<mfmaGrid, blk, 0, stream>>>(h2b, wt3d, b3, ys3, yn3, N);
    gather_f_kernel<<<gatherGrid, blk, 0, stream>>>(ys3, yn3, rowptr, cnt, colu, out, N);
}

// Round 11
// 174.090 us; speedup vs baseline: 1.1397x; 1.0819x over previous
//
#include <hip/hip_runtime.h>

static constexpr int F = 128;   // feature width of x / hidden layers

typedef __attribute__((ext_vector_type(8))) short bf16x8;
typedef __attribute__((ext_vector_type(4))) float f32x4;
typedef __attribute__((ext_vector_type(2))) float f32x2;

__device__ __forceinline__ unsigned short f2b(float f) {   // fp32 -> bf16 RNE
    unsigned int u = __float_as_uint(f);
    u += 0x7fffu + ((u >> 16) & 1u);
    return (unsigned short)(u >> 16);
}
__device__ __forceinline__ float b2f(unsigned int s) {     // low 16 bits -> fp32
    return __uint_as_float(s << 16);
}

// ---------------- fp8 e4m3fn helpers (HW cvt on gfx950; manual fallback) ----------------
#if __has_builtin(__builtin_amdgcn_cvt_pk_f32_fp8) && __has_builtin(__builtin_amdgcn_cvt_pk_fp8_f32)
#define FP8_HW 1
__device__ __forceinline__ f32x2 q2f_lo(unsigned int d) { return __builtin_amdgcn_cvt_pk_f32_fp8(d, false); }
__device__ __forceinline__ f32x2 q2f_hi(unsigned int d) { return __builtin_amdgcn_cvt_pk_f32_fp8(d, true);  }
__device__ __forceinline__ unsigned int f2q_pk4(float a, float b, float c, float d) {
    int p = __builtin_amdgcn_cvt_pk_fp8_f32(a, b, 0, false);
    p = __builtin_amdgcn_cvt_pk_fp8_f32(c, d, p, true);
    return (unsigned int)p;
}
__device__ __forceinline__ unsigned char f2q1(float v) {
    return (unsigned char)(__builtin_amdgcn_cvt_pk_fp8_f32(v, v, 0, false) & 0xff);
}
#else
__device__ __forceinline__ float q2f1(unsigned int b) {
    const unsigned s = b >> 7, e = (b >> 3) & 15, m = b & 7;
    float v = e ? __uint_as_float(((e - 7 + 127) << 23) | (m << 20))
                : (float)m * 0.001953125f;   // 2^-9
    return s ? -v : v;
}
__device__ __forceinline__ f32x2 q2f_lo(unsigned int d) { f32x2 r; r[0] = q2f1(d & 0xff); r[1] = q2f1((d >> 8) & 0xff); return r; }
__device__ __forceinline__ f32x2 q2f_hi(unsigned int d) { f32x2 r; r[0] = q2f1((d >> 16) & 0xff); r[1] = q2f1((d >> 24) & 0xff); return r; }
__device__ __forceinline__ unsigned char f2q1(float f) {
    float cf = fminf(fmaxf(f, -448.f), 448.f);
    unsigned u = __float_as_uint(cf);
    unsigned s = (u >> 31) << 7;
    int e = (int)((u >> 23) & 255) - 127;
    unsigned m = u & 0x7fffff;
    if (e < -6) return (unsigned char)s;             // flush small/denormal to 0
    unsigned keep = m >> 20, rest = m & 0xfffff;
    keep += (rest > 0x80000u) || (rest == 0x80000u && (keep & 1));
    e += (int)(keep >> 3); keep &= 7;
    if (e > 8) { e = 8; keep = 6; }                   // clamp toward 448
    return (unsigned char)(s | ((unsigned)(e + 7) << 3) | keep);
}
__device__ __forceinline__ unsigned int f2q_pk4(float a, float b, float c, float d) {
    return (unsigned)f2q1(a) | ((unsigned)f2q1(b) << 8) | ((unsigned)f2q1(c) << 16) | ((unsigned)f2q1(d) << 24);
}
#endif

// ---------------- prep: cvt x -> bf16 + fp8, cvt/transpose weights, dst histogram ----------------
// (cnt AND cursor must be zeroed by the preceding hipMemsetAsync)
__global__ __launch_bounds__(256) void prep_kernel(const float* __restrict__ x,
                                                   unsigned short* __restrict__ xb,
                                                   unsigned int* __restrict__ xq, int n4,
                                                   const int* __restrict__ dst,
                                                   int* __restrict__ cnt, int nE,
                                                   const float* __restrict__ ws1, const float* __restrict__ wn1,
                                                   const float* __restrict__ ws2, const float* __restrict__ wn2,
                                                   const float* __restrict__ ws3, const float* __restrict__ wn3,
                                                   unsigned short* __restrict__ wt1,
                                                   unsigned short* __restrict__ wt2,
                                                   unsigned short* __restrict__ wt3d) {
    const int id = blockIdx.x * 256 + threadIdx.x;
    if (id < n4) {
        const float4 v = reinterpret_cast<const float4*>(x)[id];
        uint2 o;
        o.x = (unsigned)f2b(v.x) | ((unsigned)f2b(v.y) << 16);
        o.y = (unsigned)f2b(v.z) | ((unsigned)f2b(v.w) << 16);
        reinterpret_cast<uint2*>(xb)[id] = o;
        xq[id] = f2q_pk4(v.x, v.y, v.z, v.w);
    }
    if (id < nE) atomicAdd(&cnt[dst[id]], 1);
    if (id < 128 * 256) {           // wt[col][256] concat(self, neigh), bf16, K=256
        const int k = id & 255, c = id >> 8;
        wt1[id] = f2b((k < 128) ? ws1[k * 128 + c] : wn1[(k - 128) * 128 + c]);
        wt2[id] = f2b((k < 128) ? ws2[k * 128 + c] : wn2[(k - 128) * 128 + c]);
    }
    if (id < 128 * 128) {           // layer-3 dual: wt3d[c][k], c<64 self, c>=64 neigh, K=128
        const int k = id & 127, c = id >> 7;
        wt3d[id] = f2b((c < 64) ? ws3[k * 64 + c] : wn3[k * 64 + (c - 64)]);
    }
}

// ---------------- one-kernel scan: block scan + atomic block base -> rowptr ----------------
__global__ __launch_bounds__(256) void scanAB_kernel(const int* __restrict__ cnt,
                                                     int* __restrict__ rowptr,
                                                     int* __restrict__ fillcnt,
                                                     int* __restrict__ cursor, int n) {
    __shared__ int s[256];
    __shared__ int base;
    const int tid = threadIdx.x;
    const int i = blockIdx.x * 256 + tid;
    const int v = (i < n) ? cnt[i] : 0;
    if (i < n) fillcnt[i] = 0;
    s[tid] = v;
    __syncthreads();
#pragma unroll
    for (int off = 1; off < 256; off <<= 1) {
        int t = (tid >= off) ? s[tid - off] : 0;
        __syncthreads();
        s[tid] += t;
        __syncthreads();
    }
    if (tid == 255) base = atomicAdd(cursor, s[255]);
    __syncthreads();
    if (i < n) rowptr[i] = base + s[tid] - v;   // exclusive within block + block base
}

// ---------------- CSR fill: compact ushort col (1.28 MB -> scatter absorbed by L2) ----------------
__global__ __launch_bounds__(256) void fill_kernel(const int* __restrict__ src,
                                                   const int* __restrict__ dst,
                                                   const int* __restrict__ rowptr,
                                                   int* __restrict__ fillcnt,
                                                   unsigned short* __restrict__ col, int nE) {
    const int e = blockIdx.x * 256 + threadIdx.x;
    if (e < nE) {
        const int d = dst[e];
        const int pos = atomicAdd(&fillcnt[d], 1);
        col[rowptr[d] + pos] = (unsigned short)src[e];
    }
}

// ---------------- gather (fp8 rows): nb[v] = mean_{u in N(v)} x[u]  -> bf16 ----------------
// 8 lanes per node, 16B (16 fp8) per lane -> full 128B row. 8 nodes/wave x 8-deep
// masked loop = 64 outstanding 16B loads per wave. fp32 accum via v_cvt_pk_f32_fp8.
__global__ __launch_bounds__(256) void gather_q_kernel(const unsigned char* __restrict__ xq,
                                                       const int* __restrict__ rowptr,
                                                       const int* __restrict__ deg_arr,
                                                       const unsigned short* __restrict__ col,
                                                       unsigned short* __restrict__ nb, int nNodes) {
    const int grp  = (blockIdx.x * 256 + threadIdx.x) >> 3;
    const int lane = threadIdx.x & 7;
    if (grp >= nNodes) return;
    const int beg = rowptr[grp];
    const int deg = deg_arr[grp];
    const unsigned short* __restrict__ cp = col + beg;
    const int qb = lane << 4;               // byte offset in 128B fp8 row

    float acc[16];
#pragma unroll
    for (int k = 0; k < 16; ++k) acc[k] = 0.f;

    for (int j = 0; j < deg; j += 8) {
        int   idx[8];
        float wg[8];
#pragma unroll
        for (int m = 0; m < 8; ++m) {
            const int jm = j + m;
            idx[m] = cp[jm < deg ? jm : 0];
            wg[m]  = (jm < deg) ? 1.f : 0.f;
        }
        uint4 v[8];
#pragma unroll
        for (int m = 0; m < 8; ++m)
            v[m] = *reinterpret_cast<const uint4*>(xq + (size_t)idx[m] * F + qb);
#pragma unroll
        for (int m = 0; m < 8; ++m) {
            const unsigned int dw[4] = {v[m].x, v[m].y, v[m].z, v[m].w};
#pragma unroll
            for (int d = 0; d < 4; ++d) {
                const f32x2 lo = q2f_lo(dw[d]);
                const f32x2 hi = q2f_hi(dw[d]);
                acc[4*d + 0] = fmaf(lo[0], wg[m], acc[4*d + 0]);
                acc[4*d + 1] = fmaf(lo[1], wg[m], acc[4*d + 1]);
                acc[4*d + 2] = fmaf(hi[0], wg[m], acc[4*d + 2]);
                acc[4*d + 3] = fmaf(hi[1], wg[m], acc[4*d + 3]);
            }
        }
    }

    const float inv = 1.0f / (float)(deg > 1 ? deg : 1);
    uint4 o1, o2;
    o1.x = (unsigned)f2b(acc[0] * inv)  | ((unsigned)f2b(acc[1] * inv)  << 16);
    o1.y = (unsigned)f2b(acc[2] * inv)  | ((unsigned)f2b(acc[3] * inv)  << 16);
    o1.z = (unsigned)f2b(acc[4] * inv)  | ((unsigned)f2b(acc[5] * inv)  << 16);
    o1.w = (unsigned)f2b(acc[6] * inv)  | ((unsigned)f2b(acc[7] * inv)  << 16);
    o2.x = (unsigned)f2b(acc[8] * inv)  | ((unsigned)f2b(acc[9] * inv)  << 16);
    o2.y = (unsigned)f2b(acc[10] * inv) | ((unsigned)f2b(acc[11] * inv) << 16);
    o2.z = (unsigned)f2b(acc[12] * inv) | ((unsigned)f2b(acc[13] * inv) << 16);
    o2.w = (unsigned)f2b(acc[14] * inv) | ((unsigned)f2b(acc[15] * inv) << 16);
    unsigned short* op = nb + (size_t)grp * F + (lane << 4);
    *reinterpret_cast<uint4*>(op)     = o1;
    *reinterpret_cast<uint4*>(op + 8) = o2;
}

// ---------------- final gather+add: out[v] = ys3[v] + mean_{u in N(v)} yn3q[u] ----------------
// yn3q rows are 64 fp8 = 64B. 4 lanes/node x 16B. fp32 out.
__global__ __launch_bounds__(256) void gather_f_kernel(const float* __restrict__ ys3,
                                                       const unsigned char* __restrict__ yn3q,
                                                       const int* __restrict__ rowptr,
                                                       const int* __restrict__ deg_arr,
                                                       const unsigned short* __restrict__ col,
                                                       float* __restrict__ out, int nNodes) {
    const int grp  = (blockIdx.x * 256 + threadIdx.x) >> 2;
    const int lane = threadIdx.x & 3;
    if (grp >= nNodes) return;
    const int beg = rowptr[grp];
    const int deg = deg_arr[grp];
    const unsigned short* __restrict__ cp = col + beg;
    const int qb = lane << 4;               // byte offset in 64B fp8 row

    float acc[16];
#pragma unroll
    for (int k = 0; k < 16; ++k) acc[k] = 0.f;

    for (int j = 0; j < deg; j += 8) {
        int   idx[8];
        float wg[8];
#pragma unroll
        for (int m = 0; m < 8; ++m) {
            const int jm = j + m;
            idx[m] = cp[jm < deg ? jm : 0];
            wg[m]  = (jm < deg) ? 1.f : 0.f;
        }
        uint4 v[8];
#pragma unroll
        for (int m = 0; m < 8; ++m)
            v[m] = *reinterpret_cast<const uint4*>(yn3q + (size_t)idx[m] * 64 + qb);
#pragma unroll
        for (int m = 0; m < 8; ++m) {
            const unsigned int dw[4] = {v[m].x, v[m].y, v[m].z, v[m].w};
#pragma unroll
            for (int d = 0; d < 4; ++d) {
                const f32x2 lo = q2f_lo(dw[d]);
                const f32x2 hi = q2f_hi(dw[d]);
                acc[4*d + 0] = fmaf(lo[0], wg[m], acc[4*d + 0]);
                acc[4*d + 1] = fmaf(lo[1], wg[m], acc[4*d + 1]);
                acc[4*d + 2] = fmaf(hi[0], wg[m], acc[4*d + 2]);
                acc[4*d + 3] = fmaf(hi[1], wg[m], acc[4*d + 3]);
            }
        }
    }

    const float inv = 1.0f / (float)(deg > 1 ? deg : 1);
    const float* sp = ys3 + (size_t)grp * 64 + (lane << 4);
    float*       op = out + (size_t)grp * 64 + (lane << 4);
#pragma unroll
    for (int d = 0; d < 4; ++d) {
        const float4 s = *reinterpret_cast<const float4*>(sp + d * 4);
        float4 o;
        o.x = s.x + acc[4*d + 0] * inv;
        o.y = s.y + acc[4*d + 1] * inv;
        o.z = s.z + acc[4*d + 2] * inv;
        o.w = s.w + acc[4*d + 3] * inv;
        *reinterpret_cast<float4*>(op + d * 4) = o;
    }
}

// ---------------- MFMA SAGE layer (K=256 concat, col-split waves, B reused x4) ----------------
// WRITEQ: also emit fp8 shadow copy of the output (for the next layer's gather).
template<int OUTF, bool RELU, bool OUTB, bool WRITEQ>
__global__ __launch_bounds__(256, 4) void mfma_layer(const unsigned short* __restrict__ xb,
                                                     const unsigned short* __restrict__ nbuf,
                                                     const unsigned short* __restrict__ wt,
                                                     const float* __restrict__ bias,
                                                     void* __restrict__ outp,
                                                     unsigned char* __restrict__ outq, int nRows)
{
    constexpr int CT = OUTF / 64;          // col-tiles per wave (128->2, 64->1)
    __shared__ unsigned short Acat[64 * 256];   // 32 KB

    const int tid  = threadIdx.x;
    const int row0 = blockIdx.x * 64;

    for (int i = tid; i < 2048; i += 256) {
        const int r  = i >> 5;
        const int ch = i & 31;             // 0-15 self, 16-31 neigh
        const int g  = row0 + r;
        uint4 v = make_uint4(0u, 0u, 0u, 0u);
        if (g < nRows) {
            const unsigned short* s = (ch < 16) ? xb : nbuf;
            v = *reinterpret_cast<const uint4*>(s + (size_t)g * F + (ch & 15) * 8);
        }
        const int off = (ch * 16) ^ ((r & 7) << 4);
        *reinterpret_cast<uint4*>(reinterpret_cast<char*>(Acat) + r * 512 + off) = v;
    }
    __syncthreads();

    const int lane = tid & 63;
    const int w    = tid >> 6;
    const int lm   = lane & 15;
    const int lq   = lane >> 4;
    const int colBase = w * (OUTF / 4);

    f32x4 acc[4][CT];
#pragma unroll
    for (int rt = 0; rt < 4; ++rt)
#pragma unroll
        for (int c = 0; c < CT; ++c) acc[rt][c] = f32x4{0.f, 0.f, 0.f, 0.f};

    const char* abase = reinterpret_cast<const char*>(Acat);

#pragma unroll
    for (int k0 = 0; k0 < 256; k0 += 32) {
        bf16x8 b[CT];
#pragma unroll
        for (int c = 0; c < CT; ++c)
            b[c] = *reinterpret_cast<const bf16x8*>(
                wt + (size_t)(colBase + c * 16 + lm) * 256 + k0 + lq * 8);
#pragma unroll
        for (int rt = 0; rt < 4; ++rt) {
            const int arow = rt * 16 + lm;
            const int aoff = (k0 * 2 + lq * 16) ^ ((arow & 7) << 4);
            const bf16x8 a = *reinterpret_cast<const bf16x8*>(abase + arow * 512 + aoff);
#pragma unroll
            for (int c = 0; c < CT; ++c)
                acc[rt][c] = __builtin_amdgcn_mfma_f32_16x16x32_bf16(a, b[c], acc[rt][c], 0, 0, 0);
        }
    }

#pragma unroll
    for (int rt = 0; rt < 4; ++rt) {
#pragma unroll
        for (int c = 0; c < CT; ++c) {
            const int colIdx = colBase + c * 16 + lm;
            const float bv = bias[colIdx];
#pragma unroll
            for (int i = 0; i < 4; ++i) {
                const int grow = row0 + rt * 16 + lq * 4 + i;
                if (grow >= nRows) continue;
                float v = acc[rt][c][i] + bv;
                if (RELU) v = fmaxf(v, 0.f);
                if (OUTB) ((unsigned short*)outp)[(size_t)grow * F + colIdx] = f2b(v);
                else      ((float*)outp)[(size_t)grow * OUTF + colIdx] = v;
                if (WRITEQ) outq[(size_t)grow * F + colIdx] = f2q1(v);
            }
        }
    }
}

// ---------------- layer-3 dual GEMM: ys3 = h2@Ws3+b3 (fp32), yn3q = h2@Wn3 (fp8) ----------------
__global__ __launch_bounds__(256, 4) void mfma_dual(const unsigned short* __restrict__ h2b,
                                                    const unsigned short* __restrict__ wt3d,
                                                    const float* __restrict__ bias,
                                                    float* __restrict__ ys3,
                                                    unsigned char* __restrict__ yn3q, int nRows)
{
    __shared__ unsigned short Acat[64 * 128];   // 16 KB

    const int tid  = threadIdx.x;
    const int row0 = blockIdx.x * 64;

    for (int i = tid; i < 1024; i += 256) {
        const int r  = i >> 4;
        const int ch = i & 15;
        const int g  = row0 + r;
        uint4 v = make_uint4(0u, 0u, 0u, 0u);
        if (g < nRows)
            v = *reinterpret_cast<const uint4*>(h2b + (size_t)g * F + ch * 8);
        const int off = (ch * 16) ^ ((r & 7) << 4);
        *reinterpret_cast<uint4*>(reinterpret_cast<char*>(Acat) + r * 256 + off) = v;
    }
    __syncthreads();

    const int lane = tid & 63;
    const int w    = tid >> 6;             // wave 0..3 -> col block w*32
    const int lm   = lane & 15;
    const int lq   = lane >> 4;
    const int colBase = w * 32;

    f32x4 acc[4][2];
#pragma unroll
    for (int rt = 0; rt < 4; ++rt) {
        acc[rt][0] = f32x4{0.f, 0.f, 0.f, 0.f};
        acc[rt][1] = f32x4{0.f, 0.f, 0.f, 0.f};
    }

    const char* abase = reinterpret_cast<const char*>(Acat);

#pragma unroll
    for (int k0 = 0; k0 < 128; k0 += 32) {
        bf16x8 b[2];
#pragma unroll
        for (int c = 0; c < 2; ++c)
            b[c] = *reinterpret_cast<const bf16x8*>(
                wt3d + (size_t)(colBase + c * 16 + lm) * 128 + k0 + lq * 8);
#pragma unroll
        for (int rt = 0; rt < 4; ++rt) {
            const int arow = rt * 16 + lm;
            const int aoff = (k0 * 2 + lq * 16) ^ ((arow & 7) << 4);
            const bf16x8 a = *reinterpret_cast<const bf16x8*>(abase + arow * 256 + aoff);
#pragma unroll
            for (int c = 0; c < 2; ++c)
                acc[rt][c] = __builtin_amdgcn_mfma_f32_16x16x32_bf16(a, b[c], acc[rt][c], 0, 0, 0);
        }
    }

#pragma unroll
    for (int rt = 0; rt < 4; ++rt) {
#pragma unroll
        for (int c = 0; c < 2; ++c) {
            const int colIdx = colBase + c * 16 + lm;
#pragma unroll
            for (int i = 0; i < 4; ++i) {
                const int grow = row0 + rt * 16 + lq * 4 + i;
                if (grow >= nRows) continue;
                if (colIdx < 64) {
                    ys3[(size_t)grow * 64 + colIdx] = acc[rt][c][i] + bias[colIdx];
                } else {
                    yn3q[(size_t)grow * 64 + (colIdx - 64)] = f2q1(acc[rt][c][i]);
                }
            }
        }
    }
}

extern "C" void kernel_launch(void* const* d_in, const int* in_sizes, int n_in,
                              void* d_out, int out_size, void* d_ws, size_t ws_size,
                              hipStream_t stream) {
    const float* x   = (const float*)d_in[0];
    const int*   src = (const int*)  d_in[1];
    const int*   dst = (const int*)  d_in[2];
    const float* ws1 = (const float*)d_in[3];
    const float* wn1 = (const float*)d_in[4];
    const float* b1  = (const float*)d_in[5];
    const float* ws2 = (const float*)d_in[6];
    const float* wn2 = (const float*)d_in[7];
    const float* b2  = (const float*)d_in[8];
    const float* ws3 = (const float*)d_in[9];
    const float* wn3 = (const float*)d_in[10];
    const float* b3  = (const float*)d_in[11];
    float* out = (float*)d_out;

    const int N = in_sizes[0] / F;   // 50000
    const int E = in_sizes[1];       // 640000

    const int nScanBlocks = (N + 255) / 256;   // 196

    // ---- workspace: [cnt|cursor] | rowptr | fillcnt | colu | xb | nb | h1b | h2b | xq | h1q | yn3q | ys3 | wt ----
    char* w = (char*)d_ws;
    const size_t cntBytes = ((size_t)N * 4 + 511) & ~(size_t)511;
    const size_t curBytes = 512;
    const size_t rpBytes  = ((size_t)N * 4 + 511) & ~(size_t)511;
    const size_t fcBytes  = rpBytes;
    const size_t colBytes = ((size_t)E * 2 + 511) & ~(size_t)511;
    int*            cnt     = (int*)(w);
    int*            cursor  = (int*)(w + cntBytes);
    int*            rowptr  = (int*)(w + cntBytes + curBytes);
    int*            fillcnt = (int*)(w + cntBytes + curBytes + rpBytes);
    unsigned short* colu    = (unsigned short*)(w + cntBytes + curBytes + rpBytes + fcBytes);
    unsigned short* xb      = (unsigned short*)(w + cntBytes + curBytes + rpBytes + fcBytes + colBytes);
    unsigned short* nb      = xb  + (size_t)N * F;
    unsigned short* h1b     = nb  + (size_t)N * F;
    unsigned short* h2b     = h1b + (size_t)N * F;
    unsigned char*  xq      = (unsigned char*)(h2b + (size_t)N * F);
    unsigned char*  h1q     = xq  + (size_t)N * F;
    unsigned char*  yn3q    = h1q + (size_t)N * F;          // N*64 fp8
    float*          ys3     = (float*)(yn3q + (size_t)N * 64 + 256);
    unsigned short* wt1     = (unsigned short*)(ys3 + (size_t)N * 64);
    unsigned short* wt2     = wt1 + 128 * 256;
    unsigned short* wt3d    = wt2 + 128 * 256;              // 128 cols x 128 K

    const dim3 blk(256);
    const int n4       = N * F / 4;
    const int prepGrid = (n4 + 255) / 256;
    const int edgeGrid = (E + 255) / 256;
    const int gqGrid   = (int)(((size_t)N * 8 + 255) / 256);
    const int gfGrid   = (int)(((size_t)N * 4 + 255) / 256);
    const int mfmaGrid = (N + 63) / 64;

    // ---- build compact CSR: memset -> prep(hist+cvt) -> scanAB -> fill ----
    hipMemsetAsync(cnt, 0, cntBytes + curBytes, stream);
    prep_kernel<<<prepGrid, blk, 0, stream>>>(x, xb, (unsigned int*)xq, n4, dst, cnt, E,
                                              ws1, wn1, ws2, wn2, ws3, wn3, wt1, wt2, wt3d);
    scanAB_kernel<<<nScanBlocks, blk, 0, stream>>>(cnt, rowptr, fillcnt, cursor, N);
    fill_kernel<<<edgeGrid, blk, 0, stream>>>(src, dst, rowptr, fillcnt, colu, E);

    // ---- layers 1,2: fp8 gather + MFMA GEMM (layer1 also emits h1 fp8 shadow) ----
    gather_q_kernel<<<gqGrid, blk, 0, stream>>>(xq, rowptr, cnt, colu, nb, N);
    mfma_layer<128, true, true, true ><<<mfmaGrid, blk, 0, stream>>>(xb,  nb, wt1, b1, h1b, h1q, N);

    gather_q_kernel<<<gqGrid, blk, 0, stream>>>(h1q, rowptr, cnt, colu, nb, N);
    mfma_layer<128, true, true, false><<<mfmaGrid, blk, 0, stream>>>(h1b, nb, wt2, b2, h2b, nullptr, N);

    // ---- layer 3 via linearity: dual GEMM (fp8 yn3), then 64B-row gather + add -> out ----
    mfma_dual<<<mfmaGrid, blk, 0, stream>>>(h2b, wt3d, b3, ys3, yn3q, N);
    gather_f_kernel<<<gfGrid, blk, 0, stream>>>(ys3, yn3q, rowptr, cnt, colu, out, N);
}

// Round 12
// 166.876 us; speedup vs baseline: 1.1890x; 1.0432x over previous
//
#include <hip/hip_runtime.h>

static constexpr int F = 128;   // feature width of x / hidden layers

typedef __attribute__((ext_vector_type(8))) short bf16x8;
typedef __attribute__((ext_vector_type(4))) float f32x4;
typedef __attribute__((ext_vector_type(2))) float f32x2;

__device__ __forceinline__ unsigned short f2b(float f) {   // fp32 -> bf16 RNE
    unsigned int u = __float_as_uint(f);
    u += 0x7fffu + ((u >> 16) & 1u);
    return (unsigned short)(u >> 16);
}
__device__ __forceinline__ float b2f(unsigned int s) {     // low 16 bits -> fp32
    return __uint_as_float(s << 16);
}

// ---------------- fp8 e4m3fn helpers (HW cvt on gfx950; manual fallback) ----------------
#if __has_builtin(__builtin_amdgcn_cvt_pk_f32_fp8) && __has_builtin(__builtin_amdgcn_cvt_pk_fp8_f32)
__device__ __forceinline__ f32x2 q2f_lo(unsigned int d) { return __builtin_amdgcn_cvt_pk_f32_fp8(d, false); }
__device__ __forceinline__ f32x2 q2f_hi(unsigned int d) { return __builtin_amdgcn_cvt_pk_f32_fp8(d, true);  }
__device__ __forceinline__ unsigned int f2q_pk4(float a, float b, float c, float d) {
    int p = __builtin_amdgcn_cvt_pk_fp8_f32(a, b, 0, false);
    p = __builtin_amdgcn_cvt_pk_fp8_f32(c, d, p, true);
    return (unsigned int)p;
}
__device__ __forceinline__ unsigned char f2q1(float v) {
    return (unsigned char)(__builtin_amdgcn_cvt_pk_fp8_f32(v, v, 0, false) & 0xff);
}
#else
__device__ __forceinline__ float q2f1(unsigned int b) {
    const unsigned s = b >> 7, e = (b >> 3) & 15, m = b & 7;
    float v = e ? __uint_as_float(((e - 7 + 127) << 23) | (m << 20))
                : (float)m * 0.001953125f;   // 2^-9
    return s ? -v : v;
}
__device__ __forceinline__ f32x2 q2f_lo(unsigned int d) { f32x2 r; r[0] = q2f1(d & 0xff); r[1] = q2f1((d >> 8) & 0xff); return r; }
__device__ __forceinline__ f32x2 q2f_hi(unsigned int d) { f32x2 r; r[0] = q2f1((d >> 16) & 0xff); r[1] = q2f1((d >> 24) & 0xff); return r; }
__device__ __forceinline__ unsigned char f2q1(float f) {
    float cf = fminf(fmaxf(f, -448.f), 448.f);
    unsigned u = __float_as_uint(cf);
    unsigned s = (u >> 31) << 7;
    int e = (int)((u >> 23) & 255) - 127;
    unsigned m = u & 0x7fffff;
    if (e < -6) return (unsigned char)s;             // flush small/denormal to 0
    unsigned keep = m >> 20, rest = m & 0xfffff;
    keep += (rest > 0x80000u) || (rest == 0x80000u && (keep & 1));
    e += (int)(keep >> 3); keep &= 7;
    if (e > 8) { e = 8; keep = 6; }                   // clamp toward 448
    return (unsigned char)(s | ((unsigned)(e + 7) << 3) | keep);
}
__device__ __forceinline__ unsigned int f2q_pk4(float a, float b, float c, float d) {
    return (unsigned)f2q1(a) | ((unsigned)f2q1(b) << 8) | ((unsigned)f2q1(c) << 16) | ((unsigned)f2q1(d) << 24);
}
#endif

// ---------------- prep: cvt x -> bf16 + fp8, cvt/transpose weights, dst histogram ----------------
__global__ __launch_bounds__(256) void prep_kernel(const float* __restrict__ x,
                                                   unsigned short* __restrict__ xb,
                                                   unsigned int* __restrict__ xq, int n4,
                                                   const int* __restrict__ dst,
                                                   int* __restrict__ cnt, int nE,
                                                   const float* __restrict__ ws1, const float* __restrict__ wn1,
                                                   const float* __restrict__ ws2, const float* __restrict__ wn2,
                                                   const float* __restrict__ ws3, const float* __restrict__ wn3,
                                                   unsigned short* __restrict__ wt1,
                                                   unsigned short* __restrict__ wt2,
                                                   unsigned short* __restrict__ wt3d) {
    const int id = blockIdx.x * 256 + threadIdx.x;
    if (id < n4) {
        const float4 v = reinterpret_cast<const float4*>(x)[id];
        uint2 o;
        o.x = (unsigned)f2b(v.x) | ((unsigned)f2b(v.y) << 16);
        o.y = (unsigned)f2b(v.z) | ((unsigned)f2b(v.w) << 16);
        reinterpret_cast<uint2*>(xb)[id] = o;
        xq[id] = f2q_pk4(v.x, v.y, v.z, v.w);
    }
    if (id < nE) atomicAdd(&cnt[dst[id]], 1);
    if (id < 128 * 256) {           // wt[col][256] concat(self, neigh), bf16, K=256
        const int k = id & 255, c = id >> 8;
        wt1[id] = f2b((k < 128) ? ws1[k * 128 + c] : wn1[(k - 128) * 128 + c]);
        wt2[id] = f2b((k < 128) ? ws2[k * 128 + c] : wn2[(k - 128) * 128 + c]);
    }
    if (id < 128 * 128) {           // layer-3 dual: wt3d[c][k], c<64 self, c>=64 neigh, K=128
        const int k = id & 127, c = id >> 7;
        wt3d[id] = f2b((c < 64) ? ws3[k * 64 + c] : wn3[k * 64 + (c - 64)]);
    }
}

// ---------------- one-kernel scan: block scan + atomic block base -> rowptr ----------------
__global__ __launch_bounds__(256) void scanAB_kernel(const int* __restrict__ cnt,
                                                     int* __restrict__ rowptr,
                                                     int* __restrict__ fillcnt,
                                                     int* __restrict__ cursor, int n) {
    __shared__ int s[256];
    __shared__ int base;
    const int tid = threadIdx.x;
    const int i = blockIdx.x * 256 + tid;
    const int v = (i < n) ? cnt[i] : 0;
    if (i < n) fillcnt[i] = 0;
    s[tid] = v;
    __syncthreads();
#pragma unroll
    for (int off = 1; off < 256; off <<= 1) {
        int t = (tid >= off) ? s[tid - off] : 0;
        __syncthreads();
        s[tid] += t;
        __syncthreads();
    }
    if (tid == 255) base = atomicAdd(cursor, s[255]);
    __syncthreads();
    if (i < n) rowptr[i] = base + s[tid] - v;   // exclusive within block + block base
}

// ---------------- CSR fill: compact ushort col (1.28 MB -> scatter absorbed by L2) ----------------
__global__ __launch_bounds__(256) void fill_kernel(const int* __restrict__ src,
                                                   const int* __restrict__ dst,
                                                   const int* __restrict__ rowptr,
                                                   int* __restrict__ fillcnt,
                                                   unsigned short* __restrict__ col, int nE) {
    const int e = blockIdx.x * 256 + threadIdx.x;
    if (e < nE) {
        const int d = dst[e];
        const int pos = atomicAdd(&fillcnt[d], 1);
        col[rowptr[d] + pos] = (unsigned short)src[e];
    }
}

// ---------------- gather (fp8 rows): nb[v] = mean_{u in N(v)} x[u]  -> bf16 ----------------
__global__ __launch_bounds__(256) void gather_q_kernel(const unsigned char* __restrict__ xq,
                                                       const int* __restrict__ rowptr,
                                                       const int* __restrict__ deg_arr,
                                                       const unsigned short* __restrict__ col,
                                                       unsigned short* __restrict__ nb, int nNodes) {
    const int grp  = (blockIdx.x * 256 + threadIdx.x) >> 3;
    const int lane = threadIdx.x & 7;
    if (grp >= nNodes) return;
    const int beg = rowptr[grp];
    const int deg = deg_arr[grp];
    const unsigned short* __restrict__ cp = col + beg;
    const int qb = lane << 4;               // byte offset in 128B fp8 row

    float acc[16];
#pragma unroll
    for (int k = 0; k < 16; ++k) acc[k] = 0.f;

    for (int j = 0; j < deg; j += 8) {
        int   idx[8];
        float wg[8];
#pragma unroll
        for (int m = 0; m < 8; ++m) {
            const int jm = j + m;
            idx[m] = cp[jm < deg ? jm : 0];
            wg[m]  = (jm < deg) ? 1.f : 0.f;
        }
        uint4 v[8];
#pragma unroll
        for (int m = 0; m < 8; ++m)
            v[m] = *reinterpret_cast<const uint4*>(xq + (size_t)idx[m] * F + qb);
#pragma unroll
        for (int m = 0; m < 8; ++m) {
            const unsigned int dw[4] = {v[m].x, v[m].y, v[m].z, v[m].w};
#pragma unroll
            for (int d = 0; d < 4; ++d) {
                const f32x2 lo = q2f_lo(dw[d]);
                const f32x2 hi = q2f_hi(dw[d]);
                acc[4*d + 0] = fmaf(lo[0], wg[m], acc[4*d + 0]);
                acc[4*d + 1] = fmaf(lo[1], wg[m], acc[4*d + 1]);
                acc[4*d + 2] = fmaf(hi[0], wg[m], acc[4*d + 2]);
                acc[4*d + 3] = fmaf(hi[1], wg[m], acc[4*d + 3]);
            }
        }
    }

    const float inv = 1.0f / (float)(deg > 1 ? deg : 1);
    uint4 o1, o2;
    o1.x = (unsigned)f2b(acc[0] * inv)  | ((unsigned)f2b(acc[1] * inv)  << 16);
    o1.y = (unsigned)f2b(acc[2] * inv)  | ((unsigned)f2b(acc[3] * inv)  << 16);
    o1.z = (unsigned)f2b(acc[4] * inv)  | ((unsigned)f2b(acc[5] * inv)  << 16);
    o1.w = (unsigned)f2b(acc[6] * inv)  | ((unsigned)f2b(acc[7] * inv)  << 16);
    o2.x = (unsigned)f2b(acc[8] * inv)  | ((unsigned)f2b(acc[9] * inv)  << 16);
    o2.y = (unsigned)f2b(acc[10] * inv) | ((unsigned)f2b(acc[11] * inv) << 16);
    o2.z = (unsigned)f2b(acc[12] * inv) | ((unsigned)f2b(acc[13] * inv) << 16);
    o2.w = (unsigned)f2b(acc[14] * inv) | ((unsigned)f2b(acc[15] * inv) << 16);
    unsigned short* op = nb + (size_t)grp * F + (lane << 4);
    *reinterpret_cast<uint4*>(op)     = o1;
    *reinterpret_cast<uint4*>(op + 8) = o2;
}

// ---------------- final gather+add: out[v] = ys3[v] + mean_{u in N(v)} yn3q[u] ----------------
__global__ __launch_bounds__(256) void gather_f_kernel(const float* __restrict__ ys3,
                                                       const unsigned char* __restrict__ yn3q,
                                                       const int* __restrict__ rowptr,
                                                       const int* __restrict__ deg_arr,
                                                       const unsigned short* __restrict__ col,
                                                       float* __restrict__ out, int nNodes) {
    const int grp  = (blockIdx.x * 256 + threadIdx.x) >> 2;
    const int lane = threadIdx.x & 3;
    if (grp >= nNodes) return;
    const int beg = rowptr[grp];
    const int deg = deg_arr[grp];
    const unsigned short* __restrict__ cp = col + beg;
    const int qb = lane << 4;               // byte offset in 64B fp8 row

    float acc[16];
#pragma unroll
    for (int k = 0; k < 16; ++k) acc[k] = 0.f;

    for (int j = 0; j < deg; j += 8) {
        int   idx[8];
        float wg[8];
#pragma unroll
        for (int m = 0; m < 8; ++m) {
            const int jm = j + m;
            idx[m] = cp[jm < deg ? jm : 0];
            wg[m]  = (jm < deg) ? 1.f : 0.f;
        }
        uint4 v[8];
#pragma unroll
        for (int m = 0; m < 8; ++m)
            v[m] = *reinterpret_cast<const uint4*>(yn3q + (size_t)idx[m] * 64 + qb);
#pragma unroll
        for (int m = 0; m < 8; ++m) {
            const unsigned int dw[4] = {v[m].x, v[m].y, v[m].z, v[m].w};
#pragma unroll
            for (int d = 0; d < 4; ++d) {
                const f32x2 lo = q2f_lo(dw[d]);
                const f32x2 hi = q2f_hi(dw[d]);
                acc[4*d + 0] = fmaf(lo[0], wg[m], acc[4*d + 0]);
                acc[4*d + 1] = fmaf(lo[1], wg[m], acc[4*d + 1]);
                acc[4*d + 2] = fmaf(hi[0], wg[m], acc[4*d + 2]);
                acc[4*d + 3] = fmaf(hi[1], wg[m], acc[4*d + 3]);
            }
        }
    }

    const float inv = 1.0f / (float)(deg > 1 ? deg : 1);
    const float* sp = ys3 + (size_t)grp * 64 + (lane << 4);
    float*       op = out + (size_t)grp * 64 + (lane << 4);
#pragma unroll
    for (int d = 0; d < 4; ++d) {
        const float4 s = *reinterpret_cast<const float4*>(sp + d * 4);
        float4 o;
        o.x = s.x + acc[4*d + 0] * inv;
        o.y = s.y + acc[4*d + 1] * inv;
        o.z = s.z + acc[4*d + 2] * inv;
        o.w = s.w + acc[4*d + 3] * inv;
        *reinterpret_cast<float4*>(op + d * 4) = o;
    }
}

// ---------------- layer-1 MFMA (K=256 concat, col-split waves, B reused x4) ----------------
// Writes h1 bf16 + fp8 shadow (for layer-2 gather).
__global__ __launch_bounds__(256, 4) void mfma_layer1(const unsigned short* __restrict__ xb,
                                                      const unsigned short* __restrict__ nbuf,
                                                      const unsigned short* __restrict__ wt,
                                                      const float* __restrict__ bias,
                                                      unsigned short* __restrict__ outb,
                                                      unsigned char* __restrict__ outq, int nRows)
{
    __shared__ unsigned short Acat[64 * 256];   // 32 KB

    const int tid  = threadIdx.x;
    const int row0 = blockIdx.x * 64;

    for (int i = tid; i < 2048; i += 256) {
        const int r  = i >> 5;
        const int ch = i & 31;             // 0-15 self, 16-31 neigh
        const int g  = row0 + r;
        uint4 v = make_uint4(0u, 0u, 0u, 0u);
        if (g < nRows) {
            const unsigned short* s = (ch < 16) ? xb : nbuf;
            v = *reinterpret_cast<const uint4*>(s + (size_t)g * F + (ch & 15) * 8);
        }
        const int off = (ch * 16) ^ ((r & 7) << 4);
        *reinterpret_cast<uint4*>(reinterpret_cast<char*>(Acat) + r * 512 + off) = v;
    }
    __syncthreads();

    const int lane = tid & 63;
    const int w    = tid >> 6;
    const int lm   = lane & 15;
    const int lq   = lane >> 4;
    const int colBase = w * 32;

    f32x4 acc[4][2];
#pragma unroll
    for (int rt = 0; rt < 4; ++rt) {
        acc[rt][0] = f32x4{0.f, 0.f, 0.f, 0.f};
        acc[rt][1] = f32x4{0.f, 0.f, 0.f, 0.f};
    }

    const char* abase = reinterpret_cast<const char*>(Acat);

#pragma unroll
    for (int k0 = 0; k0 < 256; k0 += 32) {
        bf16x8 b[2];
#pragma unroll
        for (int c = 0; c < 2; ++c)
            b[c] = *reinterpret_cast<const bf16x8*>(
                wt + (size_t)(colBase + c * 16 + lm) * 256 + k0 + lq * 8);
#pragma unroll
        for (int rt = 0; rt < 4; ++rt) {
            const int arow = rt * 16 + lm;
            const int aoff = (k0 * 2 + lq * 16) ^ ((arow & 7) << 4);
            const bf16x8 a = *reinterpret_cast<const bf16x8*>(abase + arow * 512 + aoff);
#pragma unroll
            for (int c = 0; c < 2; ++c)
                acc[rt][c] = __builtin_amdgcn_mfma_f32_16x16x32_bf16(a, b[c], acc[rt][c], 0, 0, 0);
        }
    }

#pragma unroll
    for (int rt = 0; rt < 4; ++rt) {
#pragma unroll
        for (int c = 0; c < 2; ++c) {
            const int colIdx = colBase + c * 16 + lm;
            const float bv = bias[colIdx];
#pragma unroll
            for (int i = 0; i < 4; ++i) {
                const int grow = row0 + rt * 16 + lq * 4 + i;
                if (grow >= nRows) continue;
                const float v = fmaxf(acc[rt][c][i] + bv, 0.f);
                outb[(size_t)grow * F + colIdx] = f2b(v);
                outq[(size_t)grow * F + colIdx] = f2q1(v);
            }
        }
    }
}

// ---------------- FUSED layer-2 + layer-3 dual GEMM ----------------
// Pass 1 (K=256, wt2): h2 = relu([h1|nb] @ wt2^T + b2) for this block's 64 rows,
// written bf16 into LDS (reusing Acat's first 16KB after a sync — no h2 global round-trip).
// Pass 2 (K=128, wt3d): ys3 = h2@Ws3+b3 (fp32), yn3q = h2@Wn3 (fp8).
__global__ __launch_bounds__(256, 4) void mfma_fused23(const unsigned short* __restrict__ h1b,
                                                       const unsigned short* __restrict__ nbuf,
                                                       const unsigned short* __restrict__ wt2,
                                                       const float* __restrict__ b2,
                                                       const unsigned short* __restrict__ wt3d,
                                                       const float* __restrict__ b3,
                                                       float* __restrict__ ys3,
                                                       unsigned char* __restrict__ yn3q, int nRows)
{
    __shared__ unsigned short Acat[64 * 256];   // 32 KB (pass-1 A; first 16KB reused as pass-2 A)

    const int tid  = threadIdx.x;
    const int row0 = blockIdx.x * 64;

    // ---- stage pass-1 A: 64 rows x (128 h1 | 128 nb) bf16, swizzled ----
    for (int i = tid; i < 2048; i += 256) {
        const int r  = i >> 5;
        const int ch = i & 31;
        const int g  = row0 + r;
        uint4 v = make_uint4(0u, 0u, 0u, 0u);
        if (g < nRows) {
            const unsigned short* s = (ch < 16) ? h1b : nbuf;
            v = *reinterpret_cast<const uint4*>(s + (size_t)g * F + (ch & 15) * 8);
        }
        const int off = (ch * 16) ^ ((r & 7) << 4);
        *reinterpret_cast<uint4*>(reinterpret_cast<char*>(Acat) + r * 512 + off) = v;
    }
    __syncthreads();

    const int lane = tid & 63;
    const int w    = tid >> 6;
    const int lm   = lane & 15;
    const int lq   = lane >> 4;
    const int colBase = w * 32;           // 32 cols per wave (128 total)

    f32x4 acc[4][2];
#pragma unroll
    for (int rt = 0; rt < 4; ++rt) {
        acc[rt][0] = f32x4{0.f, 0.f, 0.f, 0.f};
        acc[rt][1] = f32x4{0.f, 0.f, 0.f, 0.f};
    }

    const char* abase = reinterpret_cast<const char*>(Acat);

    // ---- pass 1: K=256 ----
#pragma unroll
    for (int k0 = 0; k0 < 256; k0 += 32) {
        bf16x8 b[2];
#pragma unroll
        for (int c = 0; c < 2; ++c)
            b[c] = *reinterpret_cast<const bf16x8*>(
                wt2 + (size_t)(colBase + c * 16 + lm) * 256 + k0 + lq * 8);
#pragma unroll
        for (int rt = 0; rt < 4; ++rt) {
            const int arow = rt * 16 + lm;
            const int aoff = (k0 * 2 + lq * 16) ^ ((arow & 7) << 4);
            const bf16x8 a = *reinterpret_cast<const bf16x8*>(abase + arow * 512 + aoff);
#pragma unroll
            for (int c = 0; c < 2; ++c)
                acc[rt][c] = __builtin_amdgcn_mfma_f32_16x16x32_bf16(a, b[c], acc[rt][c], 0, 0, 0);
        }
    }

    __syncthreads();   // all pass-1 LDS reads done; safe to overwrite

    // ---- epilogue 1: h2 = relu(acc + b2) -> bf16 into LDS (row stride 256B, swizzled) ----
    {
        char* a2 = reinterpret_cast<char*>(Acat);
#pragma unroll
        for (int rt = 0; rt < 4; ++rt) {
#pragma unroll
            for (int c = 0; c < 2; ++c) {
                const int colIdx = colBase + c * 16 + lm;
                const float bv = b2[colIdx];
                const int chunkOff = (colIdx >> 3) << 4;     // 16B chunk index * 16
                const int inChunk  = (colIdx & 7) << 1;
#pragma unroll
                for (int i = 0; i < 4; ++i) {
                    const int r = rt * 16 + lq * 4 + i;
                    const float v = fmaxf(acc[rt][c][i] + bv, 0.f);
                    const int off = (chunkOff ^ ((r & 7) << 4)) + inChunk;
                    *reinterpret_cast<unsigned short*>(a2 + r * 256 + off) = f2b(v);
                }
            }
        }
    }
    __syncthreads();

    // ---- pass 2: K=128, wt3d (cols 0-63 self -> ys3, 64-127 neigh -> yn3q) ----
#pragma unroll
    for (int rt = 0; rt < 4; ++rt) {
        acc[rt][0] = f32x4{0.f, 0.f, 0.f, 0.f};
        acc[rt][1] = f32x4{0.f, 0.f, 0.f, 0.f};
    }

#pragma unroll
    for (int k0 = 0; k0 < 128; k0 += 32) {
        bf16x8 b[2];
#pragma unroll
        for (int c = 0; c < 2; ++c)
            b[c] = *reinterpret_cast<const bf16x8*>(
                wt3d + (size_t)(colBase + c * 16 + lm) * 128 + k0 + lq * 8);
#pragma unroll
        for (int rt = 0; rt < 4; ++rt) {
            const int arow = rt * 16 + lm;
            const int aoff = (k0 * 2 + lq * 16) ^ ((arow & 7) << 4);
            const bf16x8 a = *reinterpret_cast<const bf16x8*>(abase + arow * 256 + aoff);
#pragma unroll
            for (int c = 0; c < 2; ++c)
                acc[rt][c] = __builtin_amdgcn_mfma_f32_16x16x32_bf16(a, b[c], acc[rt][c], 0, 0, 0);
        }
    }

    // ---- epilogue 2 ----
#pragma unroll
    for (int rt = 0; rt < 4; ++rt) {
#pragma unroll
        for (int c = 0; c < 2; ++c) {
            const int colIdx = colBase + c * 16 + lm;
#pragma unroll
            for (int i = 0; i < 4; ++i) {
                const int grow = row0 + rt * 16 + lq * 4 + i;
                if (grow >= nRows) continue;
                if (colIdx < 64) {
                    ys3[(size_t)grow * 64 + colIdx] = acc[rt][c][i] + b3[colIdx];
                } else {
                    yn3q[(size_t)grow * 64 + (colIdx - 64)] = f2q1(acc[rt][c][i]);
                }
            }
        }
    }
}

extern "C" void kernel_launch(void* const* d_in, const int* in_sizes, int n_in,
                              void* d_out, int out_size, void* d_ws, size_t ws_size,
                              hipStream_t stream) {
    const float* x   = (const float*)d_in[0];
    const int*   src = (const int*)  d_in[1];
    const int*   dst = (const int*)  d_in[2];
    const float* ws1 = (const float*)d_in[3];
    const float* wn1 = (const float*)d_in[4];
    const float* b1  = (const float*)d_in[5];
    const float* ws2 = (const float*)d_in[6];
    const float* wn2 = (const float*)d_in[7];
    const float* b2  = (const float*)d_in[8];
    const float* ws3 = (const float*)d_in[9];
    const float* wn3 = (const float*)d_in[10];
    const float* b3  = (const float*)d_in[11];
    float* out = (float*)d_out;

    const int N = in_sizes[0] / F;   // 50000
    const int E = in_sizes[1];       // 640000

    const int nScanBlocks = (N + 255) / 256;   // 196

    // ---- workspace: [cnt|cursor] | rowptr | fillcnt | colu | xb | nb | h1b | xq | h1q | yn3q | ys3 | wt ----
    char* w = (char*)d_ws;
    const size_t cntBytes = ((size_t)N * 4 + 511) & ~(size_t)511;
    const size_t curBytes = 512;
    const size_t rpBytes  = ((size_t)N * 4 + 511) & ~(size_t)511;
    const size_t fcBytes  = rpBytes;
    const size_t colBytes = ((size_t)E * 2 + 511) & ~(size_t)511;
    int*            cnt     = (int*)(w);
    int*            cursor  = (int*)(w + cntBytes);
    int*            rowptr  = (int*)(w + cntBytes + curBytes);
    int*            fillcnt = (int*)(w + cntBytes + curBytes + rpBytes);
    unsigned short* colu    = (unsigned short*)(w + cntBytes + curBytes + rpBytes + fcBytes);
    unsigned short* xb      = (unsigned short*)(w + cntBytes + curBytes + rpBytes + fcBytes + colBytes);
    unsigned short* nb      = xb  + (size_t)N * F;
    unsigned short* h1b     = nb  + (size_t)N * F;
    unsigned char*  xq      = (unsigned char*)(h1b + (size_t)N * F);
    unsigned char*  h1q     = xq  + (size_t)N * F;
    unsigned char*  yn3q    = h1q + (size_t)N * F;          // N*64 fp8
    float*          ys3     = (float*)(yn3q + (size_t)N * 64 + 256);
    unsigned short* wt1     = (unsigned short*)(ys3 + (size_t)N * 64);
    unsigned short* wt2     = wt1 + 128 * 256;
    unsigned short* wt3d    = wt2 + 128 * 256;              // 128 cols x 128 K

    const dim3 blk(256);
    const int n4       = N * F / 4;
    const int prepGrid = (n4 + 255) / 256;
    const int edgeGrid = (E + 255) / 256;
    const int gqGrid   = (int)(((size_t)N * 8 + 255) / 256);
    const int gfGrid   = (int)(((size_t)N * 4 + 255) / 256);
    const int mfmaGrid = (N + 63) / 64;

    // ---- build compact CSR: memset -> prep(hist+cvt) -> scanAB -> fill ----
    hipMemsetAsync(cnt, 0, cntBytes + curBytes, stream);
    prep_kernel<<<prepGrid, blk, 0, stream>>>(x, xb, (unsigned int*)xq, n4, dst, cnt, E,
                                              ws1, wn1, ws2, wn2, ws3, wn3, wt1, wt2, wt3d);
    scanAB_kernel<<<nScanBlocks, blk, 0, stream>>>(cnt, rowptr, fillcnt, cursor, N);
    fill_kernel<<<edgeGrid, blk, 0, stream>>>(src, dst, rowptr, fillcnt, colu, E);

    // ---- layer 1: fp8 gather + MFMA (emits h1 bf16 + fp8 shadow) ----
    gather_q_kernel<<<gqGrid, blk, 0, stream>>>(xq, rowptr, cnt, colu, nb, N);
    mfma_layer1<<<mfmaGrid, blk, 0, stream>>>(xb, nb, wt1, b1, h1b, h1q, N);

    // ---- layer 2 + layer-3 dual GEMM fused (h2 never leaves LDS) ----
    gather_q_kernel<<<gqGrid, blk, 0, stream>>>(h1q, rowptr, cnt, colu, nb, N);
    mfma_fused23<<<mfmaGrid, blk, 0, stream>>>(h1b, nb, wt2, b2, wt3d, b3, ys3, yn3q, N);

    // ---- layer 3 gather + add -> out ----
    gather_f_kernel<<<gfGrid, blk, 0, stream>>>(ys3, yn3q, rowptr, cnt, colu, out, N);
}